// Round 15
// baseline (336.278 us; speedup 1.0000x reference)
//
#include <hip/hip_runtime.h>

typedef _Float16 f16x8 __attribute__((ext_vector_type(8)));
typedef float    f32x4 __attribute__((ext_vector_type(4)));

constexpr int BATCH = 2048;
constexpr int SEQ   = 512;
constexpr int H     = 50;
constexpr int NB    = 8;     // batch per block -> 256 blocks = 1 per CU
constexpr int NT    = 896;   // 14 waves: 7 L0-role + 7 L1-role
constexpr int PSZ   = 1024;  // compact panel halfs per buffer (2 KB)

__device__ __forceinline__ float fexp2(float x) { return __builtin_amdgcn_exp2f(x); }
__device__ __forceinline__ float frcp(float x)  { return __builtin_amdgcn_rcpf(x); }
__device__ __forceinline__ _Float16 f16hi(float w) { return (_Float16)w; }
__device__ __forceinline__ _Float16 f16lo(float w) {
    _Float16 h = (_Float16)w; return (_Float16)(w - (float)h);
}
// compact B-panel address (halfs) for value (k, c), k<128, c<8 (single copy)
__device__ __forceinline__ int caddr(int k, int c) {
    return ((k >> 3) * 64) + c * 8 + (k & 7);
}
union H2U { unsigned u; _Float16 h[2]; };

constexpr float K1 = 1.4426950408889634f;   // log2(e)
constexpr float K2 = 2.8853900817779268f;   // 2*log2(e)

// === r22 (FINAL): r19 structure (session best, 279.7us) + dead-tile trim ===
// Session ledger (counter-us): r9=285 r11=294 r12=335 r13=309 r14=291
// r15=294 r16=288 r17=284 r18=358 r19=279.7 r20=310 r21=295.
// Falsified levers: LDS aggregate(r12), bank conflicts(r11), MFMA count
// (r11)/depth(r14), wave count(r14), de-phasing(r10/r13), VALU issue(r15),
// LDS-counter sync(r18), setprio wide(r20) AND narrow(r21). Wins: role-split
// with s_barrier (r19, -1.5%), compact broadcast panel (r16), gate prescale
// (r15), merged rcp (r17), multi-phase micro-cuts (r17).
// r19 counters: VALUBusy 55.8 + MfmaUtil 27.9 = ~84% combined issue, HBM
// 0.1%, conflicts 232K -> issue-mix/latency bound; no remaining lever.
// This round: r19 byte-identical + wave-uniform dead-tile guard (wave 6 L0 /
// wave 13 L1 skip their T1=13 gB chains; consuming lanes have vOK=false).
// Structure: waves 0-6 (L0) h1(s): 2 ds_read + 4 MFMA + act + 1 write; A =
// prescaled Whh0 + x hi/lo rows 50/51 (staged by wave 6's dead-tile lanes).
// waves 7-13 (L1) h2(s-1): 4 ds_read + 8 MFMA (Wih1 over h1 + Whh1 over h2,
// 2-deep chains joined) + act + 1 write. Compact single-copy broadcast panel
// (lanes nn/nn+8 share addresses -> free LDS broadcast); prescaled gates
// (-K1/-K2 folded into A/bias at setup); merged-rcp act; ONE s_barrier/step.
// body s reads sB[s&1]={h1(s-1),x(s),h2(s-2)}, writes {h1(s),x(s+1),h2(s-1)};
// edges s=0,511,512 peeled.

__global__ __launch_bounds__(NT, 3) void lstm2_r22(
    const float* __restrict__ x,
    const float* __restrict__ Wih0, const float* __restrict__ Whh0,
    const float* __restrict__ bih0, const float* __restrict__ bhh0,
    const float* __restrict__ Wih1, const float* __restrict__ Whh1,
    const float* __restrict__ bih1, const float* __restrict__ bhh1,
    const float* __restrict__ fcW,  const float* __restrict__ fcb,
    float* __restrict__ out)
{
    __shared__ _Float16 sB[2][PSZ];     // double-buffered compact panel, 4 KB
    __shared__ unsigned sXu[SEQ * NB];  // pre-split x (hi,lo), 16 KB
    __shared__ float    sH2f[H * NB];   // final h2

    const int t    = threadIdx.x;
    const int wave = t >> 6, lane = t & 63;
    const int quad = lane >> 4, nn = lane & 15;
    const int bbase = blockIdx.x * NB;

    // zero both panels (h(-1)=0 init; rows k in [52,64),[114,128) stay 0)
    for (int i = t; i < 2 * PSZ; i += NT) ((_Float16*)sB)[i] = (_Float16)0.f;

    // pre-stage ALL x as packed f16 hi/lo pairs (coalesced along s)
    for (int i = t; i < NB * SEQ; i += NT) {
        const int b = i >> 9, s = i & (SEQ - 1);
        const float xv = x[(bbase + b) * SEQ + s];
        H2U p; p.h[0] = f16hi(xv); p.h[1] = f16lo(xv);
        sXu[s * NB + b] = p.u;
    }

    const bool isL1 = (wave >= 7);
    const int  wv   = isL1 ? wave - 7 : wave;
    const bool t1v  = (wv < 6);             // tile T1 alive? (wv==6 -> T1=13 dead)
    const int  T0   = (wv < 6) ? 2 * wv     : 12;
    const int  T1   = (wv < 6) ? 2 * wv + 1 : 13;
    const int  selT = nn >> 3;              // lane's act tile: 0->T0, 1->T1
    const int  col  = nn & 7;               // batch
    const int  jjS  = (selT ? T1 : T0) * 4 + quad;
    const bool vOK  = (jjS < H);

    // ---- constant A-fragments (PRESCALED), per role ----
    f16x8 aA[2][2];            // L0: Whh0 (k<50) + x hi/lo rows 50/51
    f16x8 aI[2][2], aH[2][2];  // L1: Wih1 over h1, Whh1 over h2
    #pragma unroll
    for (int tt = 0; tt < 2; ++tt) {
        const int  m    = tt ? T1 : T0;
        const int  jr   = m * 4 + (nn >> 2);
        const int  gate = nn & 3;
        const bool rv   = (jr < H);
        const int  lrow = gate * H + jr;
        const float rsc = (gate == 2) ? -K2 : -K1;
        #pragma unroll
        for (int q = 0; q < 2; ++q) {
            #pragma unroll
            for (int j = 0; j < 8; ++j) {
                const int k = q * 32 + quad * 8 + j;
                _Float16 vA = (_Float16)0.f, vI = (_Float16)0.f, vH = (_Float16)0.f;
                if (rv) {
                    if (!isL1) {
                        if      (k < 50)  vA = (_Float16)(rsc * Whh0[lrow * H + k]);
                        else if (k == 50) vA = f16hi(rsc * Wih0[lrow]);
                        else if (k == 51) vA = f16lo(rsc * Wih0[lrow]);
                    } else if (k < 50) {
                        vI = (_Float16)(rsc * Wih1[lrow * H + k]);
                        vH = (_Float16)(rsc * Whh1[lrow * H + k]);
                    }
                }
                aA[tt][q][j] = vA; aI[tt][q][j] = vI; aH[tt][q][j] = vH;
            }
        }
    }
    f32x4 biasA = {0,0,0,0}, biasB = {0,0,0,0};
    {
        const float* bi = isL1 ? bih1 : bih0;
        const float* bh = isL1 ? bhh1 : bhh0;
        const int jqA = T0 * 4 + quad, jqB = T1 * 4 + quad;
        #pragma unroll
        for (int r = 0; r < 4; ++r) {
            const float sc = (r == 2) ? -K2 : -K1;
            biasA[r] = (jqA < H) ? sc * (bi[r * H + jqA] + bh[r * H + jqA]) : 0.f;
            biasB[r] = (jqB < H) ? sc * (bi[r * H + jqB] + bh[r * H + jqB]) : 0.f;
        }
    }

    const int rb0 = quad * 64 + col * 8;    // chunk bases (broadcast across nn/nn+8)
    const int rb1 = 256 + rb0, rb2 = 512 + rb0, rb3 = 768 + rb0;
    const int wslot = caddr((isL1 ? 64 : 0) + (vOK ? jjS : 0), col);
    const bool xst  = (!isL1) && (wv == 6) && (quad == 0) && (selT == 1);  // 8 lanes
    float c = 0.f;

    __syncthreads();
    if (t < NB)                              // x(0), rows 50/51 of panel 0
        ((unsigned*)sB[0])[193 + 4 * t] = sXu[t];
    __syncthreads();

    auto act = [&](float g0, float g1, float g2, float g3) -> float {
        float Ei = fexp2(g0);                    // e^{-i}
        float Ef = fexp2(g1);                    // e^{-f}
        float Eg = fexp2(-fabsf(g2));            // e^{-2|g~|}
        float Eo = fexp2(g3);                    // e^{-o}
        float P  = (1.f + Ei) * (1.f + Eg);
        float F  = 1.f + Ef;
        float R  = frcp(P * F);
        float tn = copysignf((1.f - Eg) * F, -g2);
        c = fmaf(c, P, tn) * R;
        float Ec = fexp2(-fabsf(K2 * c));
        return copysignf((1.f - Ec) * frcp((1.f + Eo) * (1.f + Ec)), c);
    };

    auto body = [&](int s, const _Float16* __restrict__ br,
                    _Float16* __restrict__ bw,
                    bool doL0, bool doL1, bool last) {
        if (!isL1) {
            if (doL0) {
                const f16x8 q0 = *(const f16x8*)&br[rb0];
                const f16x8 q1 = *(const f16x8*)&br[rb1];
                f32x4 gA = biasA;
                gA = __builtin_amdgcn_mfma_f32_16x16x32_f16(aA[0][0], q0, gA, 0, 0, 0);
                gA = __builtin_amdgcn_mfma_f32_16x16x32_f16(aA[0][1], q1, gA, 0, 0, 0);
                f32x4 gB = biasB;
                if (t1v) {
                    gB = __builtin_amdgcn_mfma_f32_16x16x32_f16(aA[1][0], q0, gB, 0, 0, 0);
                    gB = __builtin_amdgcn_mfma_f32_16x16x32_f16(aA[1][1], q1, gB, 0, 0, 0);
                }
                float h = act(selT ? gB[0] : gA[0], selT ? gB[1] : gA[1],
                              selT ? gB[2] : gA[2], selT ? gB[3] : gA[3]);
                if (vOK) bw[wslot] = (_Float16)h;    // h1(s)
            }
            if (xst)                                 // x(s+1) -> write panel
                ((unsigned*)bw)[193 + 4 * col] = sXu[((s + 1) & (SEQ - 1)) * NB + col];
        } else {
            if (doL1) {
                const f16x8 q0 = *(const f16x8*)&br[rb0];
                const f16x8 q1 = *(const f16x8*)&br[rb1];
                const f16x8 q2 = *(const f16x8*)&br[rb2];
                const f16x8 q3 = *(const f16x8*)&br[rb3];
                f32x4 gAa = biasA;
                gAa = __builtin_amdgcn_mfma_f32_16x16x32_f16(aI[0][0], q0, gAa, 0, 0, 0);
                gAa = __builtin_amdgcn_mfma_f32_16x16x32_f16(aI[0][1], q1, gAa, 0, 0, 0);
                f32x4 gAb = {0,0,0,0};
                gAb = __builtin_amdgcn_mfma_f32_16x16x32_f16(aH[0][0], q2, gAb, 0, 0, 0);
                gAb = __builtin_amdgcn_mfma_f32_16x16x32_f16(aH[0][1], q3, gAb, 0, 0, 0);
                f32x4 gBa = biasB, gBb = {0,0,0,0};
                if (t1v) {
                    gBa = __builtin_amdgcn_mfma_f32_16x16x32_f16(aI[1][0], q0, gBa, 0, 0, 0);
                    gBa = __builtin_amdgcn_mfma_f32_16x16x32_f16(aI[1][1], q1, gBa, 0, 0, 0);
                    gBb = __builtin_amdgcn_mfma_f32_16x16x32_f16(aH[1][0], q2, gBb, 0, 0, 0);
                    gBb = __builtin_amdgcn_mfma_f32_16x16x32_f16(aH[1][1], q3, gBb, 0, 0, 0);
                }
                float g[4];
                #pragma unroll
                for (int r = 0; r < 4; ++r)
                    g[r] = selT ? (gBa[r] + gBb[r]) : (gAa[r] + gAb[r]);
                float h = act(g[0], g[1], g[2], g[3]);
                if (vOK) {
                    if (last) sH2f[jjS * NB + col] = h;   // h2(511) for the FC
                    else      bw[wslot] = (_Float16)h;    // h2(s-1)
                }
            }
        }
        __syncthreads();   // the ONLY barrier per step (all 14 waves, always)
    };

    body(0, sB[0], sB[1], true, false, false);
    #pragma unroll 1
    for (int i = 0; i < 255; ++i) {
        body(2 * i + 1, sB[1], sB[0], true, true, false);
        body(2 * i + 2, sB[0], sB[1], true, true, false);
    }
    body(511, sB[1], sB[0], true, true, false);
    body(512, sB[0], sB[1], false, true, true);

    // ---- FC epilogue: out[b] = fcW . h2_last[b] + fcb ----
    if (t < NB) {
        float sum = fcb[0];
        #pragma unroll
        for (int jx = 0; jx < H; ++jx) sum += fcW[jx] * sH2f[jx * NB + t];
        out[bbase + t] = sum;
    }
}

extern "C" void kernel_launch(void* const* d_in, const int* in_sizes, int n_in,
                              void* d_out, int out_size, void* d_ws, size_t ws_size,
                              hipStream_t stream)
{
    const float* x    = (const float*)d_in[0];
    const float* Wih0 = (const float*)d_in[1];
    const float* Whh0 = (const float*)d_in[2];
    const float* bih0 = (const float*)d_in[3];
    const float* bhh0 = (const float*)d_in[4];
    const float* Wih1 = (const float*)d_in[5];
    const float* Whh1 = (const float*)d_in[6];
    const float* bih1 = (const float*)d_in[7];
    const float* bhh1 = (const float*)d_in[8];
    const float* fcW  = (const float*)d_in[9];
    const float* fcb  = (const float*)d_in[10];

    lstm2_r22<<<BATCH / NB, NT, 0, stream>>>(
        x, Wih0, Whh0, bih0, bhh0, Wih1, Whh1, bih1, bhh1, fcW, fcb,
        (float*)d_out);
}

// Round 16
// 315.875 us; speedup vs baseline: 1.0646x; 1.0646x over previous
//
#include <hip/hip_runtime.h>

typedef _Float16 f16x8 __attribute__((ext_vector_type(8)));
typedef float    f32x4 __attribute__((ext_vector_type(4)));

constexpr int BATCH = 2048;
constexpr int SEQ   = 512;
constexpr int H     = 50;
constexpr int NB    = 8;     // batch per block -> 256 blocks = 1 per CU
constexpr int NT    = 896;   // 14 waves: 7 L0-role + 7 L1-role
constexpr int PSZ   = 1024;  // compact panel halfs per buffer (2 KB)

__device__ __forceinline__ float fexp2(float x) { return __builtin_amdgcn_exp2f(x); }
__device__ __forceinline__ float frcp(float x)  { return __builtin_amdgcn_rcpf(x); }
__device__ __forceinline__ _Float16 f16hi(float w) { return (_Float16)w; }
__device__ __forceinline__ _Float16 f16lo(float w) {
    _Float16 h = (_Float16)w; return (_Float16)(w - (float)h);
}
// compact B-panel address (halfs) for value (k, c), k<128, c<8 (single copy)
__device__ __forceinline__ int caddr(int k, int c) {
    return ((k >> 3) * 64) + c * 8 + (k & 7);
}
union H2U { unsigned u; _Float16 h[2]; };

constexpr float K1 = 1.4426950408889634f;   // log2(e)
constexpr float K2 = 2.8853900817779268f;   // 2*log2(e)

// === FINAL: r19 byte-identical resubmission (session best, 279.7 us) ===
// Session ledger (counter-us): r9=285 r11=294 r12=335 r13=309 r14=291
// r15=294 r16=288 r17=284 r18=358 r19=279.7 r20=310 r21=295 r22=305.
// r21 (+setprio on MFMA cluster) and r22 (+dead-tile branch) both regressed
// 15-25us off r19 -> the r19 codegen is a tight issue-packing optimum;
// any hot-loop perturbation loses more than it saves.
// Falsified levers: LDS aggregate(r12), bank conflicts(r11), MFMA count
// (r11)/depth(r14), wave count(r14), de-phasing(r10/r13), VALU issue(r15),
// LDS-counter sync(r18), setprio wide(r20)/narrow(r21), hot-loop branch
// trim(r22). Wins kept here: role-split + s_barrier (r19), compact
// single-copy broadcast panel (r16), gate prescale (r15), merged rcp (r17),
// x-in-panel hi/lo rows 50/51 (r17).
// r19 counters: VALUBusy 55.8 + MfmaUtil 27.9 ~= 84% combined issue,
// HBM 0.1%, conflicts 232K -> issue-mix/latency bound, no remaining lever.
// Structure: waves 0-6 (L0) h1(s): 2 ds_read + 4 MFMA + act + 1 write;
//   A = prescaled Whh0 + x hi/lo rows 50/51 (staged by wave 6 dead lanes).
// waves 7-13 (L1) h2(s-1): 4 ds_read + 8 MFMA (Wih1 over h1 + Whh1 over
//   h2, 2-deep chains joined) + act + 1 write.
// body s reads sB[s&1]={h1(s-1),x(s),h2(s-2)}, writes {h1(s),x(s+1),h2(s-1)};
// ONE s_barrier/step; edges s=0,511,512 peeled. Act: prescaled gates
// (-K1/-K2 folded into A/bias), merged-rcp. absmax 4.8828e-4.

__global__ __launch_bounds__(NT, 3) void lstm2_rs(
    const float* __restrict__ x,
    const float* __restrict__ Wih0, const float* __restrict__ Whh0,
    const float* __restrict__ bih0, const float* __restrict__ bhh0,
    const float* __restrict__ Wih1, const float* __restrict__ Whh1,
    const float* __restrict__ bih1, const float* __restrict__ bhh1,
    const float* __restrict__ fcW,  const float* __restrict__ fcb,
    float* __restrict__ out)
{
    __shared__ _Float16 sB[2][PSZ];     // double-buffered compact panel, 4 KB
    __shared__ unsigned sXu[SEQ * NB];  // pre-split x (hi,lo), 16 KB
    __shared__ float    sH2f[H * NB];   // final h2

    const int t    = threadIdx.x;
    const int wave = t >> 6, lane = t & 63;
    const int quad = lane >> 4, nn = lane & 15;
    const int bbase = blockIdx.x * NB;

    // zero both panels (h(-1)=0 init; rows k in [52,64),[114,128) stay 0)
    for (int i = t; i < 2 * PSZ; i += NT) ((_Float16*)sB)[i] = (_Float16)0.f;

    // pre-stage ALL x as packed f16 hi/lo pairs (coalesced along s)
    for (int i = t; i < NB * SEQ; i += NT) {
        const int b = i >> 9, s = i & (SEQ - 1);
        const float xv = x[(bbase + b) * SEQ + s];
        H2U p; p.h[0] = f16hi(xv); p.h[1] = f16lo(xv);
        sXu[s * NB + b] = p.u;
    }

    const bool isL1 = (wave >= 7);
    const int  wv   = isL1 ? wave - 7 : wave;
    const int  T0   = (wv < 6) ? 2 * wv     : 12;
    const int  T1   = (wv < 6) ? 2 * wv + 1 : 13;   // 13 = dead tile
    const int  selT = nn >> 3;              // lane's act tile: 0->T0, 1->T1
    const int  col  = nn & 7;               // batch
    const int  jjS  = (selT ? T1 : T0) * 4 + quad;
    const bool vOK  = (jjS < H);

    // ---- constant A-fragments (PRESCALED), per role ----
    f16x8 aA[2][2];            // L0: Whh0 (k<50) + x hi/lo rows 50/51
    f16x8 aI[2][2], aH[2][2];  // L1: Wih1 over h1, Whh1 over h2
    #pragma unroll
    for (int tt = 0; tt < 2; ++tt) {
        const int  m    = tt ? T1 : T0;
        const int  jr   = m * 4 + (nn >> 2);
        const int  gate = nn & 3;
        const bool rv   = (jr < H);
        const int  lrow = gate * H + jr;
        const float rsc = (gate == 2) ? -K2 : -K1;
        #pragma unroll
        for (int q = 0; q < 2; ++q) {
            #pragma unroll
            for (int j = 0; j < 8; ++j) {
                const int k = q * 32 + quad * 8 + j;
                _Float16 vA = (_Float16)0.f, vI = (_Float16)0.f, vH = (_Float16)0.f;
                if (rv) {
                    if (!isL1) {
                        if      (k < 50)  vA = (_Float16)(rsc * Whh0[lrow * H + k]);
                        else if (k == 50) vA = f16hi(rsc * Wih0[lrow]);
                        else if (k == 51) vA = f16lo(rsc * Wih0[lrow]);
                    } else if (k < 50) {
                        vI = (_Float16)(rsc * Wih1[lrow * H + k]);
                        vH = (_Float16)(rsc * Whh1[lrow * H + k]);
                    }
                }
                aA[tt][q][j] = vA; aI[tt][q][j] = vI; aH[tt][q][j] = vH;
            }
        }
    }
    f32x4 biasA = {0,0,0,0}, biasB = {0,0,0,0};
    {
        const float* bi = isL1 ? bih1 : bih0;
        const float* bh = isL1 ? bhh1 : bhh0;
        const int jqA = T0 * 4 + quad, jqB = T1 * 4 + quad;
        #pragma unroll
        for (int r = 0; r < 4; ++r) {
            const float sc = (r == 2) ? -K2 : -K1;
            biasA[r] = (jqA < H) ? sc * (bi[r * H + jqA] + bh[r * H + jqA]) : 0.f;
            biasB[r] = (jqB < H) ? sc * (bi[r * H + jqB] + bh[r * H + jqB]) : 0.f;
        }
    }

    const int rb0 = quad * 64 + col * 8;    // chunk bases (broadcast across nn/nn+8)
    const int rb1 = 256 + rb0, rb2 = 512 + rb0, rb3 = 768 + rb0;
    const int wslot = caddr((isL1 ? 64 : 0) + (vOK ? jjS : 0), col);
    const bool xst  = (!isL1) && (wv == 6) && (quad == 0) && (selT == 1);  // 8 lanes
    float c = 0.f;

    __syncthreads();
    if (t < NB)                              // x(0), rows 50/51 of panel 0
        ((unsigned*)sB[0])[193 + 4 * t] = sXu[t];
    __syncthreads();

    auto act = [&](float g0, float g1, float g2, float g3) -> float {
        float Ei = fexp2(g0);                    // e^{-i}
        float Ef = fexp2(g1);                    // e^{-f}
        float Eg = fexp2(-fabsf(g2));            // e^{-2|g~|}
        float Eo = fexp2(g3);                    // e^{-o}
        float P  = (1.f + Ei) * (1.f + Eg);
        float F  = 1.f + Ef;
        float R  = frcp(P * F);
        float tn = copysignf((1.f - Eg) * F, -g2);
        c = fmaf(c, P, tn) * R;
        float Ec = fexp2(-fabsf(K2 * c));
        return copysignf((1.f - Ec) * frcp((1.f + Eo) * (1.f + Ec)), c);
    };

    auto body = [&](int s, const _Float16* __restrict__ br,
                    _Float16* __restrict__ bw,
                    bool doL0, bool doL1, bool last) {
        if (!isL1) {
            if (doL0) {
                const f16x8 q0 = *(const f16x8*)&br[rb0];
                const f16x8 q1 = *(const f16x8*)&br[rb1];
                f32x4 gA = biasA;
                gA = __builtin_amdgcn_mfma_f32_16x16x32_f16(aA[0][0], q0, gA, 0, 0, 0);
                gA = __builtin_amdgcn_mfma_f32_16x16x32_f16(aA[0][1], q1, gA, 0, 0, 0);
                f32x4 gB = biasB;
                gB = __builtin_amdgcn_mfma_f32_16x16x32_f16(aA[1][0], q0, gB, 0, 0, 0);
                gB = __builtin_amdgcn_mfma_f32_16x16x32_f16(aA[1][1], q1, gB, 0, 0, 0);
                float h = act(selT ? gB[0] : gA[0], selT ? gB[1] : gA[1],
                              selT ? gB[2] : gA[2], selT ? gB[3] : gA[3]);
                if (vOK) bw[wslot] = (_Float16)h;    // h1(s)
            }
            if (xst)                                 // x(s+1) -> write panel
                ((unsigned*)bw)[193 + 4 * col] = sXu[((s + 1) & (SEQ - 1)) * NB + col];
        } else {
            if (doL1) {
                const f16x8 q0 = *(const f16x8*)&br[rb0];
                const f16x8 q1 = *(const f16x8*)&br[rb1];
                const f16x8 q2 = *(const f16x8*)&br[rb2];
                const f16x8 q3 = *(const f16x8*)&br[rb3];
                f32x4 gAa = biasA;
                gAa = __builtin_amdgcn_mfma_f32_16x16x32_f16(aI[0][0], q0, gAa, 0, 0, 0);
                gAa = __builtin_amdgcn_mfma_f32_16x16x32_f16(aI[0][1], q1, gAa, 0, 0, 0);
                f32x4 gAb = {0,0,0,0};
                gAb = __builtin_amdgcn_mfma_f32_16x16x32_f16(aH[0][0], q2, gAb, 0, 0, 0);
                gAb = __builtin_amdgcn_mfma_f32_16x16x32_f16(aH[0][1], q3, gAb, 0, 0, 0);
                f32x4 gBa = biasB;
                gBa = __builtin_amdgcn_mfma_f32_16x16x32_f16(aI[1][0], q0, gBa, 0, 0, 0);
                gBa = __builtin_amdgcn_mfma_f32_16x16x32_f16(aI[1][1], q1, gBa, 0, 0, 0);
                f32x4 gBb = {0,0,0,0};
                gBb = __builtin_amdgcn_mfma_f32_16x16x32_f16(aH[1][0], q2, gBb, 0, 0, 0);
                gBb = __builtin_amdgcn_mfma_f32_16x16x32_f16(aH[1][1], q3, gBb, 0, 0, 0);
                float g[4];
                #pragma unroll
                for (int r = 0; r < 4; ++r)
                    g[r] = selT ? (gBa[r] + gBb[r]) : (gAa[r] + gAb[r]);
                float h = act(g[0], g[1], g[2], g[3]);
                if (vOK) {
                    if (last) sH2f[jjS * NB + col] = h;   // h2(511) for the FC
                    else      bw[wslot] = (_Float16)h;    // h2(s-1)
                }
            }
        }
        __syncthreads();   // the ONLY barrier per step (all 14 waves, always)
    };

    body(0, sB[0], sB[1], true, false, false);
    #pragma unroll 1
    for (int i = 0; i < 255; ++i) {
        body(2 * i + 1, sB[1], sB[0], true, true, false);
        body(2 * i + 2, sB[0], sB[1], true, true, false);
    }
    body(511, sB[1], sB[0], true, true, false);
    body(512, sB[0], sB[1], false, true, true);

    // ---- FC epilogue: out[b] = fcW . h2_last[b] + fcb ----
    if (t < NB) {
        float sum = fcb[0];
        #pragma unroll
        for (int jx = 0; jx < H; ++jx) sum += fcW[jx] * sH2f[jx * NB + t];
        out[bbase + t] = sum;
    }
}

extern "C" void kernel_launch(void* const* d_in, const int* in_sizes, int n_in,
                              void* d_out, int out_size, void* d_ws, size_t ws_size,
                              hipStream_t stream)
{
    const float* x    = (const float*)d_in[0];
    const float* Wih0 = (const float*)d_in[1];
    const float* Whh0 = (const float*)d_in[2];
    const float* bih0 = (const float*)d_in[3];
    const float* bhh0 = (const float*)d_in[4];
    const float* Wih1 = (const float*)d_in[5];
    const float* Whh1 = (const float*)d_in[6];
    const float* bih1 = (const float*)d_in[7];
    const float* bhh1 = (const float*)d_in[8];
    const float* fcW  = (const float*)d_in[9];
    const float* fcb  = (const float*)d_in[10];

    lstm2_rs<<<BATCH / NB, NT, 0, stream>>>(
        x, Wih0, Whh0, bih0, bhh0, Wih1, Whh1, bih1, bhh1, fcW, fcb,
        (float*)d_out);
}